// Round 3
// baseline (724.146 us; speedup 1.0000x reference)
//
#include <hip/hip_runtime.h>
#include <hip/hip_bf16.h>

#define H 1024
#define F 4096
#define NE 8
#define T 4096

typedef unsigned short u16;
typedef float floatx4 __attribute__((ext_vector_type(4)));
typedef short short8 __attribute__((ext_vector_type(8)));

__device__ __forceinline__ u16 f2bf(float f) {
  union { float f; unsigned int u; } c; c.f = f;
  unsigned int u = c.u;
  return (u16)((u + 0x7fffu + ((u >> 16) & 1u)) >> 16);
}

// tanh-form GELU in sigmoid shape: 0.5x(1+tanh(y)) = x * 1/(1+e^{-2y})
__device__ __forceinline__ float gelu_f(float x) {
  float x3 = x * x * x;
  float m2y = -1.5957691216f * x - 0.0713548162f * x3;   // -2y
  float u = __expf(m2y);
  return x * __builtin_amdgcn_rcpf(1.0f + u);
}

// async global->LDS, 16B per lane. LDS dest must be uniform base + lane*16.
__device__ __forceinline__ void load16_lds(const u16* g, u16* l) {
  __builtin_amdgcn_global_load_lds(
      (const __attribute__((address_space(1))) unsigned int*)g,
      (__attribute__((address_space(3))) unsigned int*)l, 16, 0, 0);
}

// ---------------- router + x->bf16 convert: one wave per token ----------------
__global__ __launch_bounds__(256) void router_kernel(
    const float* __restrict__ x, const float* __restrict__ Wr,
    int* __restrict__ cnt, int* __restrict__ tok, float* __restrict__ wgt,
    u16* __restrict__ xb) {
  int t = (blockIdx.x * 256 + threadIdx.x) >> 6;
  int lane = threadIdx.x & 63;
  const float* xr = x + (size_t)t * H;
  double p[NE];
#pragma unroll
  for (int e = 0; e < NE; ++e) p[e] = 0.0;
  for (int k = lane; k < H; k += 64) {
    float xv = xr[k];
    const float4* wr4 = reinterpret_cast<const float4*>(Wr + k * NE);
    float4 a = wr4[0], b = wr4[1];
    p[0] += (double)xv * a.x; p[1] += (double)xv * a.y;
    p[2] += (double)xv * a.z; p[3] += (double)xv * a.w;
    p[4] += (double)xv * b.x; p[5] += (double)xv * b.y;
    p[6] += (double)xv * b.z; p[7] += (double)xv * b.w;
  }
#pragma unroll
  for (int e = 0; e < NE; ++e) {
#pragma unroll
    for (int off = 32; off; off >>= 1) p[e] += __shfl_down(p[e], off, 64);
  }
  if (lane == 0) {
    int i0 = 0;
#pragma unroll
    for (int e = 1; e < NE; ++e) if (p[e] > p[i0]) i0 = e;
    int i1 = (i0 == 0) ? 1 : 0;
#pragma unroll
    for (int e = 0; e < NE; ++e) if (e != i0 && p[e] > p[i1]) i1 = e;
    double d = exp(p[i1] - p[i0]);
    float w0 = (float)(1.0 / (1.0 + d));
    float w1 = (float)(d / (1.0 + d));
    int pos0 = atomicAdd(&cnt[i0], 1);
    tok[i0 * T + pos0] = t; wgt[i0 * T + pos0] = w0;
    int pos1 = atomicAdd(&cnt[i1], 1);
    tok[i1 * T + pos1] = t; wgt[i1 * T + pos1] = w1;
  }
  // fused convert: this block's 4 tokens -> bf16 (1024 float4 chunks)
  const float4* xs4 = reinterpret_cast<const float4*>(x + (size_t)blockIdx.x * 4 * H);
  ushort4* xd4 = reinterpret_cast<ushort4*>(xb + (size_t)blockIdx.x * 4 * H);
#pragma unroll
  for (int i = 0; i < 4; ++i) {
    float4 v = xs4[threadIdx.x + i * 256];
    ushort4 o;
    o.x = f2bf(v.x); o.y = f2bf(v.y); o.z = f2bf(v.z); o.w = f2bf(v.w);
    xd4[threadIdx.x + i * 256] = o;
  }
}

__global__ void offsets_kernel(const int* __restrict__ cnt, int* __restrict__ off) {
  if (threadIdx.x == 0) {
    int s = 0;
#pragma unroll
    for (int e = 0; e < NE; ++e) { off[e] = s; s += cnt[e]; }
    off[NE] = s;
  }
}

// ---------------- [E][R][C] f32 -> [E][C][R] bf16, 64x64 tiles ----------------
__global__ __launch_bounds__(256) void transpose_bf16_kernel(
    const float* __restrict__ src, u16* __restrict__ dst, int R, int C) {
  __shared__ u16 tile[64][72];
  int e = blockIdx.z;
  int c0 = blockIdx.x << 6, r0 = blockIdx.y << 6;
  const float* s = src + (size_t)e * R * C;
  u16* d = dst + (size_t)e * R * C;
  int t = threadIdx.x;
  int rl = t >> 4, cl = (t & 15) << 2;
#pragma unroll
  for (int i = 0; i < 4; ++i) {
    float4 v = *reinterpret_cast<const float4*>(&s[(size_t)(r0 + rl + i * 16) * C + c0 + cl]);
    ushort4 o; o.x = f2bf(v.x); o.y = f2bf(v.y); o.z = f2bf(v.z); o.w = f2bf(v.w);
    *reinterpret_cast<ushort4*>(&tile[rl + i * 16][cl]) = o;
  }
  __syncthreads();
  int cl2 = t >> 4, rl2 = (t & 15) << 2;
#pragma unroll
  for (int i = 0; i < 4; ++i) {
    ushort4 o;
    o.x = tile[rl2 + 0][cl2 + i * 16];
    o.y = tile[rl2 + 1][cl2 + i * 16];
    o.z = tile[rl2 + 2][cl2 + i * 16];
    o.w = tile[rl2 + 3][cl2 + i * 16];
    *reinterpret_cast<ushort4*>(&d[(size_t)(c0 + cl2 + i * 16) * R + r0 + rl2]) = o;
  }
}

// ---------------- GEMM1: Hc = gelu(gather(Xb) @ W1t^T + b1) ----------------
// grid: (F/128, 32 m-tiles, NE). 256 thr = 4 waves (2x2 of 64x64).
__global__ __launch_bounds__(256) void gemm1_kernel(
    const u16* __restrict__ Xb, const u16* __restrict__ W1t,
    const float* __restrict__ b1, const int* __restrict__ cnt,
    const int* __restrict__ off, const int* __restrict__ tok,
    u16* __restrict__ Hc) {
  int e = blockIdx.z;
  int n = cnt[e];
  int m0 = blockIdx.y << 7;
  if (m0 >= n) return;
  int n0 = blockIdx.x << 7;
  int rb = off[e];

  __shared__ alignas(16) u16 As[128 * 32];
  __shared__ alignas(16) u16 Bs[128 * 32];
  __shared__ alignas(16) u16 Cs[128][72];   // epilogue staging (one 64-col half)
  __shared__ int tokS[128];

  int tid = threadIdx.x;
  if (tid < 128) {
    int s = m0 + tid;
    tokS[tid] = (s < n) ? tok[e * T + s] : 0;
  }
  __syncthreads();

  const u16* W1e = W1t + (size_t)e * F * H;
  const u16* aP0 = Xb + (size_t)tokS[tid >> 2] * H + (tid & 3) * 8;
  const u16* aP1 = Xb + (size_t)tokS[64 + (tid >> 2)] * H + (tid & 3) * 8;
  const u16* bP0 = W1e + (size_t)(n0 + (tid >> 2)) * H + (tid & 3) * 8;
  const u16* bP1 = W1e + (size_t)(n0 + 64 + (tid >> 2)) * H + (tid & 3) * 8;
  u16* aL0 = &As[tid * 8];        u16* aL1 = &As[(tid + 256) * 8];
  u16* bL0 = &Bs[tid * 8];        u16* bL1 = &Bs[(tid + 256) * 8];

  int wv = tid >> 6, lane = tid & 63;
  int wm = wv >> 1, wn = wv & 1;
  int quad = lane >> 4, l16 = lane & 15;

  floatx4 acc[4][4];
#pragma unroll
  for (int mt = 0; mt < 4; ++mt)
#pragma unroll
    for (int nt = 0; nt < 4; ++nt) acc[mt][nt] = floatx4{0.f, 0.f, 0.f, 0.f};

  const u16* aF[4]; const u16* bF[4];
#pragma unroll
  for (int i = 0; i < 4; ++i) {
    aF[i] = &As[(wm * 64 + i * 16 + l16) * 32 + quad * 8];
    bF[i] = &Bs[(wn * 64 + i * 16 + l16) * 32 + quad * 8];
  }

  for (int k0 = 0; k0 < H; k0 += 32) {
    load16_lds(aP0 + k0, aL0);
    load16_lds(aP1 + k0, aL1);
    load16_lds(bP0 + k0, bL0);
    load16_lds(bP1 + k0, bL1);
    __syncthreads();
    short8 av[4], bv[4];
#pragma unroll
    for (int i = 0; i < 4; ++i) {
      av[i] = *reinterpret_cast<const short8*>(aF[i]);
      bv[i] = *reinterpret_cast<const short8*>(bF[i]);
    }
#pragma unroll
    for (int mt = 0; mt < 4; ++mt)
#pragma unroll
      for (int nt = 0; nt < 4; ++nt)
        acc[mt][nt] = __builtin_amdgcn_mfma_f32_16x16x32_bf16(av[mt], bv[nt], acc[mt][nt], 0, 0, 0);
    __syncthreads();
  }

  // epilogue: bias + fast gelu -> bf16, staged via LDS for coalesced stores.
  float b1v[4];
#pragma unroll
  for (int nt = 0; nt < 4; ++nt)
    b1v[nt] = b1[e * F + n0 + wn * 64 + nt * 16 + l16];

#pragma unroll
  for (int p = 0; p < 2; ++p) {
    __syncthreads();
    if (wn == p) {
#pragma unroll
      for (int mt = 0; mt < 4; ++mt)
#pragma unroll
        for (int i = 0; i < 4; ++i) {
          int row = wm * 64 + mt * 16 + quad * 4 + i;
#pragma unroll
          for (int nt = 0; nt < 4; ++nt)
            Cs[row][nt * 16 + l16] = f2bf(gelu_f(acc[mt][nt][i] + b1v[nt]));
        }
    }
    __syncthreads();
    int row = tid >> 1, c0 = (tid & 1) * 32;
    if (m0 + row < n) {
      u16* dst = Hc + (size_t)(rb + m0 + row) * F + n0 + p * 64 + c0;
#pragma unroll
      for (int j = 0; j < 4; ++j)
        *reinterpret_cast<short8*>(dst + j * 8) =
            *reinterpret_cast<const short8*>(&Cs[row][c0 + j * 8]);
    }
  }
}

// ---------------- GEMM2: out += w * (Hc @ W2t^T + b2), split-K x2 ----------------
// grid: (H/128, 32 m-tiles, NE*2). atomic fp32 epilogue into zeroed out.
__global__ __launch_bounds__(256) void gemm2_kernel(
    const u16* __restrict__ Hc, const u16* __restrict__ W2t,
    const float* __restrict__ b2, const int* __restrict__ cnt,
    const int* __restrict__ off, const int* __restrict__ tok,
    const float* __restrict__ wgt, float* __restrict__ out) {
  int e = blockIdx.z >> 1;
  int kh = blockIdx.z & 1;
  int n = cnt[e];
  int m0 = blockIdx.y << 7;
  if (m0 >= n) return;
  int n0 = blockIdx.x << 7;
  int rb = off[e];
  int kbase = kh * (F / 2);

  __shared__ alignas(16) u16 As[128 * 32];
  __shared__ alignas(16) u16 Bs[128 * 32];

  int tid = threadIdx.x;
  const u16* W2e = W2t + (size_t)e * F * H;
  const u16* aP0 = Hc + (size_t)(rb + m0 + (tid >> 2)) * F + kbase + (tid & 3) * 8;
  const u16* aP1 = Hc + (size_t)(rb + m0 + 64 + (tid >> 2)) * F + kbase + (tid & 3) * 8;
  const u16* bP0 = W2e + (size_t)(n0 + (tid >> 2)) * F + kbase + (tid & 3) * 8;
  const u16* bP1 = W2e + (size_t)(n0 + 64 + (tid >> 2)) * F + kbase + (tid & 3) * 8;
  u16* aL0 = &As[tid * 8];        u16* aL1 = &As[(tid + 256) * 8];
  u16* bL0 = &Bs[tid * 8];        u16* bL1 = &Bs[(tid + 256) * 8];

  int wv = tid >> 6, lane = tid & 63;
  int wm = wv >> 1, wn = wv & 1;
  int quad = lane >> 4, l16 = lane & 15;

  floatx4 acc[4][4];
#pragma unroll
  for (int mt = 0; mt < 4; ++mt)
#pragma unroll
    for (int nt = 0; nt < 4; ++nt) acc[mt][nt] = floatx4{0.f, 0.f, 0.f, 0.f};

  const u16* aF[4]; const u16* bF[4];
#pragma unroll
  for (int i = 0; i < 4; ++i) {
    aF[i] = &As[(wm * 64 + i * 16 + l16) * 32 + quad * 8];
    bF[i] = &Bs[(wn * 64 + i * 16 + l16) * 32 + quad * 8];
  }

  for (int k0 = 0; k0 < F / 2; k0 += 32) {
    load16_lds(aP0 + k0, aL0);
    load16_lds(aP1 + k0, aL1);
    load16_lds(bP0 + k0, bL0);
    load16_lds(bP1 + k0, bL1);
    __syncthreads();
    short8 av[4], bv[4];
#pragma unroll
    for (int i = 0; i < 4; ++i) {
      av[i] = *reinterpret_cast<const short8*>(aF[i]);
      bv[i] = *reinterpret_cast<const short8*>(bF[i]);
    }
#pragma unroll
    for (int mt = 0; mt < 4; ++mt)
#pragma unroll
      for (int nt = 0; nt < 4; ++nt)
        acc[mt][nt] = __builtin_amdgcn_mfma_f32_16x16x32_bf16(av[mt], bv[nt], acc[mt][nt], 0, 0, 0);
    __syncthreads();
  }

  float b2v[4];
#pragma unroll
  for (int nt = 0; nt < 4; ++nt)
    b2v[nt] = (kh == 0) ? b2[e * H + n0 + wn * 64 + nt * 16 + l16] : 0.0f;
#pragma unroll
  for (int mt = 0; mt < 4; ++mt) {
#pragma unroll
    for (int i = 0; i < 4; ++i) {
      int row = wm * 64 + mt * 16 + quad * 4 + i;
      int gr = m0 + row;
      if (gr < n) {
        float wv2 = wgt[e * T + gr];
        int tk = tok[e * T + gr];
        float* orow = out + (size_t)tk * H + n0 + wn * 64 + l16;
#pragma unroll
        for (int nt = 0; nt < 4; ++nt)
          atomicAdd(orow + nt * 16, (acc[mt][nt][i] + b2v[nt]) * wv2);
      }
    }
  }
}

extern "C" void kernel_launch(void* const* d_in, const int* in_sizes, int n_in,
                              void* d_out, int out_size, void* d_ws, size_t ws_size,
                              hipStream_t stream) {
  const float* x  = (const float*)d_in[0];
  const float* Wr = (const float*)d_in[1];
  const float* W1 = (const float*)d_in[2];
  const float* b1 = (const float*)d_in[3];
  const float* W2 = (const float*)d_in[4];
  const float* b2 = (const float*)d_in[5];
  float* out = (float*)d_out;

  char* ws = (char*)d_ws;
  // cnt@0 off@256 tok@4096(128K) wgt@135168(128K) Xb@266240(8M)
  // W1t@8654848(64M) W2t@75763712(64M) Hc@142872576(64M) -> ~200MB
  int*   cnt = (int*)(ws + 0);
  int*   off = (int*)(ws + 256);
  int*   tok = (int*)(ws + 4096);
  float* wgt = (float*)(ws + 135168);
  u16*   Xb  = (u16*)(ws + 266240);
  u16*   W1t = (u16*)(ws + 8654848);
  u16*   W2t = (u16*)(ws + 75763712);
  u16*   Hc  = (u16*)(ws + 142872576);

  hipMemsetAsync(cnt, 0, 64, stream);
  hipMemsetAsync(out, 0, (size_t)out_size * sizeof(float), stream);

  router_kernel<<<dim3(T / 4), dim3(256), 0, stream>>>(x, Wr, cnt, tok, wgt, Xb);
  offsets_kernel<<<dim3(1), dim3(64), 0, stream>>>(cnt, off);
  transpose_bf16_kernel<<<dim3(F / 64, H / 64, NE), dim3(256), 0, stream>>>(W1, W1t, H, F);
  transpose_bf16_kernel<<<dim3(H / 64, F / 64, NE), dim3(256), 0, stream>>>(W2, W2t, F, H);
  gemm1_kernel<<<dim3(F / 128, 32, NE), dim3(256), 0, stream>>>(Xb, W1t, b1, cnt, off, tok, Hc);
  gemm2_kernel<<<dim3(H / 128, 32, NE * 2), dim3(256), 0, stream>>>(Hc, W2t, b2, cnt, off, tok, wgt, out);
}

// Round 4
// 719.119 us; speedup vs baseline: 1.0070x; 1.0070x over previous
//
#include <hip/hip_runtime.h>
#include <hip/hip_bf16.h>

#define H 1024
#define F 4096
#define NE 8
#define T 4096

typedef unsigned short u16;
typedef unsigned int u32;
typedef float floatx4 __attribute__((ext_vector_type(4)));
typedef short short8 __attribute__((ext_vector_type(8)));

__device__ __forceinline__ u16 f2bf(float f) {
  union { float f; u32 u; } c; c.f = f;
  u32 u = c.u;
  return (u16)((u + 0x7fffu + ((u >> 16) & 1u)) >> 16);
}

// packed f32x2 -> bf16x2 (v_cvt_pk_bf16_f32 on gfx950); low u16 = a, high = b
__device__ __forceinline__ u32 pkbf(float a, float b) {
  __hip_bfloat162 h = __float22bfloat162_rn(float2{a, b});
  u32 r; __builtin_memcpy(&r, &h, 4); return r;
}

// tanh-form GELU in sigmoid shape: 0.5x(1+tanh(y)) = x * 1/(1+e^{-2y})
__device__ __forceinline__ float gelu_f(float x) {
  float x3 = x * x * x;
  float m2y = -1.5957691216f * x - 0.0713548162f * x3;   // -2y
  float u = __expf(m2y);
  return x * __builtin_amdgcn_rcpf(1.0f + u);
}

// async global->LDS, 16B per lane. LDS dest must be uniform base + lane*size.
__device__ __forceinline__ void load16_lds(const u16* g, u16* l) {
  __builtin_amdgcn_global_load_lds(
      (const __attribute__((address_space(1))) unsigned int*)g,
      (__attribute__((address_space(3))) unsigned int*)l, 16, 0, 0);
}

// ---------------- router + x->bf16 convert: one wave per token ----------------
__global__ __launch_bounds__(256) void router_kernel(
    const float* __restrict__ x, const float* __restrict__ Wr,
    int* __restrict__ cnt, int* __restrict__ tok, float* __restrict__ wgt,
    u16* __restrict__ xb) {
  int t = (blockIdx.x * 256 + threadIdx.x) >> 6;
  int lane = threadIdx.x & 63;
  const float* xr = x + (size_t)t * H;
  double p[NE];
#pragma unroll
  for (int e = 0; e < NE; ++e) p[e] = 0.0;
  for (int k = lane; k < H; k += 64) {
    float xv = xr[k];
    const float4* wr4 = reinterpret_cast<const float4*>(Wr + k * NE);
    float4 a = wr4[0], b = wr4[1];
    p[0] += (double)xv * a.x; p[1] += (double)xv * a.y;
    p[2] += (double)xv * a.z; p[3] += (double)xv * a.w;
    p[4] += (double)xv * b.x; p[5] += (double)xv * b.y;
    p[6] += (double)xv * b.z; p[7] += (double)xv * b.w;
  }
#pragma unroll
  for (int e = 0; e < NE; ++e) {
#pragma unroll
    for (int off = 32; off; off >>= 1) p[e] += __shfl_down(p[e], off, 64);
  }
  if (lane == 0) {
    int i0 = 0;
#pragma unroll
    for (int e = 1; e < NE; ++e) if (p[e] > p[i0]) i0 = e;
    int i1 = (i0 == 0) ? 1 : 0;
#pragma unroll
    for (int e = 0; e < NE; ++e) if (e != i0 && p[e] > p[i1]) i1 = e;
    double d = exp(p[i1] - p[i0]);
    float w0 = (float)(1.0 / (1.0 + d));
    float w1 = (float)(d / (1.0 + d));
    int pos0 = atomicAdd(&cnt[i0], 1);
    tok[i0 * T + pos0] = t; wgt[i0 * T + pos0] = w0;
    int pos1 = atomicAdd(&cnt[i1], 1);
    tok[i1 * T + pos1] = t; wgt[i1 * T + pos1] = w1;
  }
  // fused convert: this block's 4 tokens -> bf16
  const float4* xs4 = reinterpret_cast<const float4*>(x + (size_t)blockIdx.x * 4 * H);
  uint2* xd = reinterpret_cast<uint2*>(xb + (size_t)blockIdx.x * 4 * H);
#pragma unroll
  for (int i = 0; i < 4; ++i) {
    float4 v = xs4[threadIdx.x + i * 256];
    uint2 o; o.x = pkbf(v.x, v.y); o.y = pkbf(v.z, v.w);
    xd[threadIdx.x + i * 256] = o;
  }
}

// ---------------- transpose v2: [E][R][C] f32 -> [E][C][R] bf16, 128x128 ----
// LDS tl[rp][c] u32 (c-major, stride 132): u32 = bf16 rows (2rp, 2rp+1) at col c.
__global__ __launch_bounds__(256) void transpose_v2_kernel(
    const float* __restrict__ src, u16* __restrict__ dst, int R, int C) {
  __shared__ u32 tl[64 * 132];   // 33.8 KB
  int e = blockIdx.z;
  int r0 = blockIdx.y << 7, c0 = blockIdx.x << 7;
  const float* s = src + (size_t)e * R * C;
  u16* d = dst + (size_t)e * R * C;
  int tid = threadIdx.x;
  int cq = tid & 31, rp0 = tid >> 5;
#pragma unroll
  for (int it = 0; it < 8; ++it) {
    int rp = rp0 + it * 8;
    float4 u = *reinterpret_cast<const float4*>(&s[(size_t)(r0 + 2 * rp) * C + c0 + 4 * cq]);
    float4 v = *reinterpret_cast<const float4*>(&s[(size_t)(r0 + 2 * rp + 1) * C + c0 + 4 * cq]);
    uint4 q;
    q.x = pkbf(u.x, v.x); q.y = pkbf(u.y, v.y);
    q.z = pkbf(u.z, v.z); q.w = pkbf(u.w, v.w);
    *reinterpret_cast<uint4*>(&tl[rp * 132 + 4 * cq]) = q;   // ds_write_b128, conflict-free
  }
  __syncthreads();
  int c_l = tid >> 2, rq = tid & 3;
#pragma unroll
  for (int pass = 0; pass < 2; ++pass) {
#pragma unroll
    for (int it2 = 0; it2 < 4; ++it2) {
      int c = pass * 64 + c_l;
      int chunk = rq + 4 * it2;              // 16 chunks of 8 rows each
      uint4 q;
      q.x = tl[(4 * chunk + 0) * 132 + c];
      q.y = tl[(4 * chunk + 1) * 132 + c];
      q.z = tl[(4 * chunk + 2) * 132 + c];
      q.w = tl[(4 * chunk + 3) * 132 + c];
      // lanes 0-3: same col row-chunks 0..3 -> 64B contiguous store segments
      *reinterpret_cast<uint4*>(&d[(size_t)(c0 + c) * R + r0 + chunk * 8]) = q;
    }
  }
}

// ---------------- GEMM1: Hc = gelu(gather(Xb) @ W1t^T + b1) ----------------
// grid: (F/128, 32 m-tiles, NE). 256 thr = 4 waves (2x2 of 64x64).
__global__ __launch_bounds__(256) void gemm1_kernel(
    const u16* __restrict__ Xb, const u16* __restrict__ W1t,
    const float* __restrict__ b1, const int* __restrict__ cnt,
    const int* __restrict__ tok, u16* __restrict__ Hc) {
  int e = blockIdx.z;
  int n = cnt[e];
  int m0 = blockIdx.y << 7;
  if (m0 >= n) return;
  int n0 = blockIdx.x << 7;
  int rb = 0;
#pragma unroll
  for (int i = 0; i < NE; ++i) rb += (i < e) ? cnt[i] : 0;

  // As = SH[0..4095], Bs = SH[4096..8191]; Cs (epilogue) aliases SH[0..9215]
  __shared__ alignas(16) u16 SH[9216];
  __shared__ int tokS[128];
  u16* As = SH;
  u16* Bs = SH + 4096;

  int tid = threadIdx.x;
  if (tid < 128) {
    int s = m0 + tid;
    tokS[tid] = (s < n) ? tok[e * T + s] : 0;
  }
  __syncthreads();

  const u16* W1e = W1t + (size_t)e * F * H;
  const u16* aP0 = Xb + (size_t)tokS[tid >> 2] * H + (tid & 3) * 8;
  const u16* aP1 = Xb + (size_t)tokS[64 + (tid >> 2)] * H + (tid & 3) * 8;
  const u16* bP0 = W1e + (size_t)(n0 + (tid >> 2)) * H + (tid & 3) * 8;
  const u16* bP1 = W1e + (size_t)(n0 + 64 + (tid >> 2)) * H + (tid & 3) * 8;
  u16* aL0 = &As[tid * 8];        u16* aL1 = &As[(tid + 256) * 8];
  u16* bL0 = &Bs[tid * 8];        u16* bL1 = &Bs[(tid + 256) * 8];

  int wv = tid >> 6, lane = tid & 63;
  int wm = wv >> 1, wn = wv & 1;
  int quad = lane >> 4, l16 = lane & 15;

  floatx4 acc[4][4];
#pragma unroll
  for (int mt = 0; mt < 4; ++mt)
#pragma unroll
    for (int nt = 0; nt < 4; ++nt) acc[mt][nt] = floatx4{0.f, 0.f, 0.f, 0.f};

  const u16* aF[4]; const u16* bF[4];
#pragma unroll
  for (int i = 0; i < 4; ++i) {
    aF[i] = &As[(wm * 64 + i * 16 + l16) * 32 + quad * 8];
    bF[i] = &Bs[(wn * 64 + i * 16 + l16) * 32 + quad * 8];
  }

  for (int k0 = 0; k0 < H; k0 += 32) {
    load16_lds(aP0 + k0, aL0);
    load16_lds(aP1 + k0, aL1);
    load16_lds(bP0 + k0, bL0);
    load16_lds(bP1 + k0, bL1);
    __syncthreads();
    short8 av[4], bv[4];
#pragma unroll
    for (int i = 0; i < 4; ++i) {
      av[i] = *reinterpret_cast<const short8*>(aF[i]);
      bv[i] = *reinterpret_cast<const short8*>(bF[i]);
    }
#pragma unroll
    for (int mt = 0; mt < 4; ++mt)
#pragma unroll
      for (int nt = 0; nt < 4; ++nt)
        acc[mt][nt] = __builtin_amdgcn_mfma_f32_16x16x32_bf16(av[mt], bv[nt], acc[mt][nt], 0, 0, 0);
    __syncthreads();
  }

  // epilogue: bias + fast gelu -> bf16, staged via aliased LDS, coalesced stores
  float b1v[4];
#pragma unroll
  for (int nt = 0; nt < 4; ++nt)
    b1v[nt] = b1[e * F + n0 + wn * 64 + nt * 16 + l16];

#pragma unroll
  for (int p = 0; p < 2; ++p) {
    __syncthreads();
    if (wn == p) {
#pragma unroll
      for (int mt = 0; mt < 4; ++mt)
#pragma unroll
        for (int i = 0; i < 4; ++i) {
          int row = wm * 64 + mt * 16 + quad * 4 + i;
#pragma unroll
          for (int nt = 0; nt < 4; ++nt)
            SH[row * 72 + nt * 16 + l16] = f2bf(gelu_f(acc[mt][nt][i] + b1v[nt]));
        }
    }
    __syncthreads();
    int row = tid >> 1, cc = (tid & 1) * 32;
    if (m0 + row < n) {
      u16* dst = Hc + (size_t)(rb + m0 + row) * F + n0 + p * 64 + cc;
#pragma unroll
      for (int j = 0; j < 4; ++j)
        *reinterpret_cast<short8*>(dst + j * 8) =
            *reinterpret_cast<const short8*>(&SH[row * 72 + cc + j * 8]);
    }
  }
}

// ---------------- GEMM2: out += w * (Hc @ W2t^T + b2), split-K x2 ----------------
__global__ __launch_bounds__(256) void gemm2_kernel(
    const u16* __restrict__ Hc, const u16* __restrict__ W2t,
    const float* __restrict__ b2, const int* __restrict__ cnt,
    const int* __restrict__ tok, const float* __restrict__ wgt,
    float* __restrict__ out) {
  int e = blockIdx.z >> 1;
  int kh = blockIdx.z & 1;
  int n = cnt[e];
  int m0 = blockIdx.y << 7;
  if (m0 >= n) return;
  int n0 = blockIdx.x << 7;
  int rb = 0;
#pragma unroll
  for (int i = 0; i < NE; ++i) rb += (i < e) ? cnt[i] : 0;
  int kbase = kh * (F / 2);

  __shared__ alignas(16) u16 As[128 * 32];
  __shared__ alignas(16) u16 Bs[128 * 32];

  int tid = threadIdx.x;
  const u16* W2e = W2t + (size_t)e * F * H;
  const u16* aP0 = Hc + (size_t)(rb + m0 + (tid >> 2)) * F + kbase + (tid & 3) * 8;
  const u16* aP1 = Hc + (size_t)(rb + m0 + 64 + (tid >> 2)) * F + kbase + (tid & 3) * 8;
  const u16* bP0 = W2e + (size_t)(n0 + (tid >> 2)) * F + kbase + (tid & 3) * 8;
  const u16* bP1 = W2e + (size_t)(n0 + 64 + (tid >> 2)) * F + kbase + (tid & 3) * 8;
  u16* aL0 = &As[tid * 8];        u16* aL1 = &As[(tid + 256) * 8];
  u16* bL0 = &Bs[tid * 8];        u16* bL1 = &Bs[(tid + 256) * 8];

  int wv = tid >> 6, lane = tid & 63;
  int wm = wv >> 1, wn = wv & 1;
  int quad = lane >> 4, l16 = lane & 15;

  floatx4 acc[4][4];
#pragma unroll
  for (int mt = 0; mt < 4; ++mt)
#pragma unroll
    for (int nt = 0; nt < 4; ++nt) acc[mt][nt] = floatx4{0.f, 0.f, 0.f, 0.f};

  const u16* aF[4]; const u16* bF[4];
#pragma unroll
  for (int i = 0; i < 4; ++i) {
    aF[i] = &As[(wm * 64 + i * 16 + l16) * 32 + quad * 8];
    bF[i] = &Bs[(wn * 64 + i * 16 + l16) * 32 + quad * 8];
  }

  for (int k0 = 0; k0 < F / 2; k0 += 32) {
    load16_lds(aP0 + k0, aL0);
    load16_lds(aP1 + k0, aL1);
    load16_lds(bP0 + k0, bL0);
    load16_lds(bP1 + k0, bL1);
    __syncthreads();
    short8 av[4], bv[4];
#pragma unroll
    for (int i = 0; i < 4; ++i) {
      av[i] = *reinterpret_cast<const short8*>(aF[i]);
      bv[i] = *reinterpret_cast<const short8*>(bF[i]);
    }
#pragma unroll
    for (int mt = 0; mt < 4; ++mt)
#pragma unroll
      for (int nt = 0; nt < 4; ++nt)
        acc[mt][nt] = __builtin_amdgcn_mfma_f32_16x16x32_bf16(av[mt], bv[nt], acc[mt][nt], 0, 0, 0);
    __syncthreads();
  }

  float b2v[4];
#pragma unroll
  for (int nt = 0; nt < 4; ++nt)
    b2v[nt] = (kh == 0) ? b2[e * H + n0 + wn * 64 + nt * 16 + l16] : 0.0f;
#pragma unroll
  for (int mt = 0; mt < 4; ++mt) {
#pragma unroll
    for (int i = 0; i < 4; ++i) {
      int row = wm * 64 + mt * 16 + quad * 4 + i;
      int gr = m0 + row;
      if (gr < n) {
        float wv2 = wgt[e * T + gr];
        int tk = tok[e * T + gr];
        float* orow = out + (size_t)tk * H + n0 + wn * 64 + l16;
#pragma unroll
        for (int nt = 0; nt < 4; ++nt)
          atomicAdd(orow + nt * 16, (acc[mt][nt][i] + b2v[nt]) * wv2);
      }
    }
  }
}

extern "C" void kernel_launch(void* const* d_in, const int* in_sizes, int n_in,
                              void* d_out, int out_size, void* d_ws, size_t ws_size,
                              hipStream_t stream) {
  const float* x  = (const float*)d_in[0];
  const float* Wr = (const float*)d_in[1];
  const float* W1 = (const float*)d_in[2];
  const float* b1 = (const float*)d_in[3];
  const float* W2 = (const float*)d_in[4];
  const float* b2 = (const float*)d_in[5];
  float* out = (float*)d_out;

  char* ws = (char*)d_ws;
  int*   cnt = (int*)(ws + 0);
  int*   tok = (int*)(ws + 4096);
  float* wgt = (float*)(ws + 135168);
  u16*   Xb  = (u16*)(ws + 266240);
  u16*   W1t = (u16*)(ws + 8654848);
  u16*   W2t = (u16*)(ws + 75763712);
  u16*   Hc  = (u16*)(ws + 142872576);

  hipMemsetAsync(cnt, 0, 64, stream);
  hipMemsetAsync(out, 0, (size_t)out_size * sizeof(float), stream);

  router_kernel<<<dim3(T / 4), dim3(256), 0, stream>>>(x, Wr, cnt, tok, wgt, Xb);
  transpose_v2_kernel<<<dim3(F / 128, H / 128, NE), dim3(256), 0, stream>>>(W1, W1t, H, F);
  transpose_v2_kernel<<<dim3(H / 128, F / 128, NE), dim3(256), 0, stream>>>(W2, W2t, F, H);
  gemm1_kernel<<<dim3(F / 128, 32, NE), dim3(256), 0, stream>>>(Xb, W1t, b1, cnt, tok, Hc);
  gemm2_kernel<<<dim3(H / 128, 32, NE * 2), dim3(256), 0, stream>>>(Hc, W2t, b2, cnt, tok, wgt, out);
}